// Round 8
// baseline (777.053 us; speedup 1.0000x reference)
//
#include <hip/hip_runtime.h>

#define BATCH 512
#define NN    32
#define NVT   32
#define HS    501
#define VS    533
#define KP    512

typedef short bf16x8 __attribute__((ext_vector_type(8)));
typedef float f32x4  __attribute__((ext_vector_type(4)));

__device__ __forceinline__ unsigned short f2bf(float f) {
    unsigned int u = __float_as_uint(f);
    u += 0x7fffu + ((u >> 16) & 1u);
    return (unsigned short)(u >> 16);
}
__device__ __forceinline__ float bf2f(unsigned short s) {
    return __uint_as_float(((unsigned int)s) << 16);
}
__device__ __forceinline__ float sigmoidf_(float x) { return 1.0f / (1.0f + __expf(-x)); }
__device__ __forceinline__ float tanhf_(float x)    { return 1.0f - 2.0f / (1.0f + __expf(2.0f * x)); }

#define N_WHH  (3 * KP * KP)
#define N_WGM  (2 * KP * KP)
#define N_GI   (3 * NVT * KP)
#define N_IDW  (2 * NN * KP)
#define N_WRT  (KP * NN)
#define N_MSGB (BATCH * KP)
#define N_MSGF (BATCH * KP)
#define N_ADJC (BATCH * NN)
#define N_TOT  (N_WHH + N_WGM + N_GI + N_IDW + N_WRT + N_MSGB + N_MSGF + N_ADJC)

// One-time: bf16 weight repack (b_hh folded at k=501), gi table, id/bg table,
// WregT, Msg init (bf16 + f32), adjacency column bitmasks.
__global__ void prep_kernel(const float* __restrict__ W_hh, const float* __restrict__ Wg,
                            const float* __restrict__ Wm, const float* __restrict__ W_ih,
                            const float* __restrict__ b_ih, const float* __restrict__ b_hh,
                            const float* __restrict__ bg, const float* __restrict__ W_reg,
                            const float* __restrict__ adj,
                            unsigned short* __restrict__ Whh_p, unsigned short* __restrict__ Wgm_p,
                            float* __restrict__ gi_tab, float* __restrict__ idw,
                            float* __restrict__ WregT, unsigned short* __restrict__ MsgB,
                            float* __restrict__ MsgF, unsigned int* __restrict__ adjcG)
{
    for (int i = blockIdx.x * blockDim.x + threadIdx.x; i < N_TOT; i += gridDim.x * blockDim.x) {
        int j = i;
        if (j < N_WHH) {
            int g = j >> 18, rem = j & (KP * KP - 1);
            int h = rem >> 9, k = rem & (KP - 1);
            float val = 0.0f;
            if (h < HS) {
                if (k < HS)        val = W_hh[(size_t)(g * HS + h) * HS + k];
                else if (k == HS)  val = b_hh[g * HS + h];   // bias folded at k=501
            }
            Whh_p[j] = f2bf(val);
            continue;
        }
        j -= N_WHH;
        if (j < N_WGM) {
            int m = j >> 18, rem = j & (KP * KP - 1);
            int h = rem >> 9, k = rem & (KP - 1);
            const float* src = m ? Wm : Wg;
            Wgm_p[j] = (h < HS && k < HS) ? f2bf(src[(size_t)h * VS + k]) : (unsigned short)0;
            continue;
        }
        j -= N_WGM;
        if (j < N_GI) {
            int g = j >> 14, typ = (j >> 9) & 31, h = j & (KP - 1);
            gi_tab[j] = (h < HS) ? (W_ih[(size_t)(g * HS + h) * NVT + typ] + b_ih[g * HS + h]) : 0.0f;
            continue;
        }
        j -= N_GI;
        if (j < N_IDW) {
            int m = j >> 14, v = (j >> 9) & 31, h = j & (KP - 1);
            float val = 0.0f;
            if (h < HS)
                val = m ? Wm[(size_t)h * VS + HS + v]
                        : (Wg[(size_t)h * VS + HS + v] + bg[h]);
            idw[j] = val;
            continue;
        }
        j -= N_IDW;
        if (j < N_WRT) {
            int k = j >> 5, ii = j & 31;
            WregT[j] = (k < HS) ? W_reg[(size_t)ii * HS + k] : 0.0f;
            continue;
        }
        j -= N_WRT;
        if (j < N_MSGB) {
            int k = j & (KP - 1);
            MsgB[j] = (k == HS) ? (unsigned short)0x3F80 : (unsigned short)0;  // bias col = 1.0
            continue;
        }
        j -= N_MSGB;
        if (j < N_MSGF) { MsgF[j] = 0.0f; continue; }
        j -= N_MSGF;
        {
            int b = j >> 5, vp = j & 31;
            unsigned int bits = 0;
            #pragma unroll
            for (int u = 0; u < 32; u++)
                bits |= (adj[((size_t)b * NN + u) * NN + vp] != 0.0f ? 1u : 0u) << u;
            adjcG[j] = bits;
        }
    }
}

// Step A: gh = Msg @ Whh^T (3 gates) + GRU epilogue -> HvB (bf16) [+ HvF at v=31].
// grid (32, 8), block 512 (8 waves = 4 h-tiles x split-K2); 2 waves/SIMD.
__global__ __launch_bounds__(512) void gru_kernel(
    const unsigned short* __restrict__ MsgB,  // [512][512] bf16 (bias col 501 = 1)
    const float* __restrict__ MsgF,           // [512][512] f32
    const unsigned short* __restrict__ Whh,   // [3*512][512] bf16
    const float* __restrict__ gi_tab,         // [3][32][512]
    const int* __restrict__ types,            // [512][32]
    unsigned short* __restrict__ HvB,         // [512][512] bf16
    float* __restrict__ HvF,                  // [512][512] f32 (last step)
    int v)
{
    __shared__ float part[4][3][256];         // [q][gate][row*16+c16]
    const int t = threadIdx.x;
    const int lane = t & 63, w = t >> 6;
    const int c16 = lane & 15, kg = lane >> 4;
    const int q = w >> 1, kh = w & 1;         // h-subtile, K-half
    const int bb = blockIdx.x * 16;
    const int hw = blockIdx.y * 64 + q * 16;
    const int k0 = kh * 256 + kg * 8;

    const unsigned short* Ar = MsgB + (((size_t)(bb + c16)) << 9) + k0;
    const unsigned short* w0 = Whh + (((size_t)(0 * KP + hw + c16)) << 9) + k0;
    const unsigned short* w1 = Whh + (((size_t)(1 * KP + hw + c16)) << 9) + k0;
    const unsigned short* w2 = Whh + (((size_t)(2 * KP + hw + c16)) << 9) + k0;

    f32x4 a0 = {0.f,0.f,0.f,0.f}, a1 = a0, a2 = a0;
    #pragma unroll
    for (int kk = 0; kk < 8; kk++) {
        const bf16x8 af = *(const bf16x8*)(Ar + kk * 32);
        a0 = __builtin_amdgcn_mfma_f32_16x16x32_bf16(af, *(const bf16x8*)(w0 + kk * 32), a0, 0, 0, 0);
        a1 = __builtin_amdgcn_mfma_f32_16x16x32_bf16(af, *(const bf16x8*)(w1 + kk * 32), a1, 0, 0, 0);
        a2 = __builtin_amdgcn_mfma_f32_16x16x32_bf16(af, *(const bf16x8*)(w2 + kk * 32), a2, 0, 0, 0);
    }

    if (kh == 1) {
        #pragma unroll
        for (int j = 0; j < 4; j++) {
            const int pi = (kg * 4 + j) * 16 + c16;
            part[q][0][pi] = a0[j];
            part[q][1][pi] = a1[j];
            part[q][2][pi] = a2[j];
        }
    }
    __syncthreads();
    if (kh == 0) {
        const int h = hw + c16;
        const bool ok = (h < HS);
        const bool last = (v == NN - 1);
        #pragma unroll
        for (int j = 0; j < 4; j++) {
            const int pi = (kg * 4 + j) * 16 + c16;
            const float s0 = a0[j] + part[q][0][pi];
            const float s1 = a1[j] + part[q][1][pi];
            const float s2 = a2[j] + part[q][2][pi];
            const int b = bb + kg * 4 + j;
            float hv = 0.0f;
            if (ok) {
                const int typ = types[b * NN + v];
                const float gr = gi_tab[(0 * NVT + typ) * KP + h];
                const float gz = gi_tab[(1 * NVT + typ) * KP + h];
                const float gn = gi_tab[(2 * NVT + typ) * KP + h];
                const float hmsg = MsgF[((size_t)b << 9) + h];
                const float r = sigmoidf_(gr + s0);
                const float z = sigmoidf_(gz + s1);
                const float n = tanhf_(gn + r * s2);
                hv = (1.0f - z) * n + z * hmsg;
            }
            HvB[((size_t)b << 9) + h] = f2bf(hv);
            if (last) HvF[((size_t)b << 9) + h] = hv;
        }
    }
}

// Step B: z = Hv @ {Wg,Wm}^T ; G_v = sigmoid(zg+id+bg)*(zm+id) -> Gbuf;
// gather Msg_{v+1}[b,h] = sum_{u<=v} edge(u,v+1) * G_u[b,h]  (+bias col).
// grid (32, 8), block 512 (8 waves = 4 h-tiles x split-K2).
__global__ __launch_bounds__(512) void gate_kernel(
    const unsigned short* __restrict__ HvB,   // [512][512] bf16
    const unsigned short* __restrict__ Wgm,   // [2*512][512] bf16
    const float* __restrict__ idw,            // [2][32][512]
    const unsigned int* __restrict__ adjcG,   // [512][32] bitmask over u
    unsigned short* __restrict__ Gbuf,        // [32][512][512] bf16
    unsigned short* __restrict__ MsgB,        // [512][512] bf16
    float* __restrict__ MsgF,                 // [512][512] f32
    int v)
{
    __shared__ float part[4][2][256];
    const int t = threadIdx.x;
    const int lane = t & 63, w = t >> 6;
    const int c16 = lane & 15, kg = lane >> 4;
    const int q = w >> 1, kh = w & 1;
    const int bb = blockIdx.x * 16;
    const int hw = blockIdx.y * 64 + q * 16;
    const int k0 = kh * 256 + kg * 8;

    const unsigned short* Ar = HvB + (((size_t)(bb + c16)) << 9) + k0;
    const unsigned short* w0 = Wgm + (((size_t)(0 * KP + hw + c16)) << 9) + k0;
    const unsigned short* w1 = Wgm + (((size_t)(1 * KP + hw + c16)) << 9) + k0;

    f32x4 b0 = {0.f,0.f,0.f,0.f}, b1 = b0;
    #pragma unroll
    for (int kk = 0; kk < 8; kk++) {
        const bf16x8 af = *(const bf16x8*)(Ar + kk * 32);
        b0 = __builtin_amdgcn_mfma_f32_16x16x32_bf16(af, *(const bf16x8*)(w0 + kk * 32), b0, 0, 0, 0);
        b1 = __builtin_amdgcn_mfma_f32_16x16x32_bf16(af, *(const bf16x8*)(w1 + kk * 32), b1, 0, 0, 0);
    }

    if (kh == 1) {
        #pragma unroll
        for (int j = 0; j < 4; j++) {
            const int pi = (kg * 4 + j) * 16 + c16;
            part[q][0][pi] = b0[j];
            part[q][1][pi] = b1[j];
        }
    }
    __syncthreads();
    if (kh == 0) {
        const int h = hw + c16;
        const bool ok = (h < HS);
        const float id0 = ok ? idw[(0 * NN + v) * KP + h] : 0.0f;
        const float id1 = ok ? idw[(1 * NN + v) * KP + h] : 0.0f;
        #pragma unroll
        for (int j = 0; j < 4; j++) {
            const int pi = (kg * 4 + j) * 16 + c16;
            const float s0 = b0[j] + part[q][0][pi];
            const float s1 = b1[j] + part[q][1][pi];
            const int b = bb + kg * 4 + j;
            float gq = 0.0f;
            if (ok) gq = sigmoidf_(s0 + id0) * (s1 + id1);
            const unsigned short gbits = f2bf(gq);
            Gbuf[(((size_t)v << 9) + b) * KP + h] = gbits;

            float msg = 0.0f;
            unsigned int mask = adjcG[b * NN + (v + 1)];     // bits u <= v only (triu)
            if ((mask >> v) & 1u) { msg += bf2f(gbits); mask &= ~(1u << v); }
            while (mask) {
                const int u = __builtin_ctz(mask); mask &= mask - 1u;
                msg += bf2f(Gbuf[(((size_t)u << 9) + b) * KP + h]);
            }
            if (h == HS) msg = 1.0f;                          // bias column
            MsgB[((size_t)b << 9) + h] = f2bf(msg);
            MsgF[((size_t)b << 9) + h] = msg;
        }
    }
}

// mu = Hv31 @ W_reg^T + b_reg
__global__ __launch_bounds__(256) void final_kernel(
    const float* __restrict__ HvF,       // [512][512]
    const float* __restrict__ WregT,     // [512][32]
    const float* __restrict__ b_reg,     // [32]
    float* __restrict__ out)             // [512][32]
{
    const int t = blockIdx.x * 256 + threadIdx.x;
    const int b = t >> 5, i = t & 31;
    float s = b_reg[i];
    const float* hp = HvF + ((size_t)b << 9);
    #pragma unroll 4
    for (int k = 0; k < KP; k++) s += hp[k] * WregT[k * 32 + i];
    out[b * 32 + i] = s;
}

extern "C" void kernel_launch(void* const* d_in, const int* in_sizes, int n_in,
                              void* d_out, int out_size, void* d_ws, size_t ws_size,
                              hipStream_t stream) {
    const int*   node_types = (const int*)  d_in[0];
    const float* adj        = (const float*)d_in[1];
    const float* Wg         = (const float*)d_in[2];
    const float* bg         = (const float*)d_in[3];
    const float* Wm         = (const float*)d_in[4];
    const float* W_ih       = (const float*)d_in[5];
    const float* b_ih       = (const float*)d_in[6];
    const float* W_hh       = (const float*)d_in[7];
    const float* b_hh       = (const float*)d_in[8];
    const float* W_reg      = (const float*)d_in[9];
    const float* b_reg      = (const float*)d_in[10];
    float* out = (float*)d_out;

    char* p = (char*)d_ws;
    unsigned short* Whh_p = (unsigned short*)p; p += (size_t)N_WHH * 2;
    unsigned short* Wgm_p = (unsigned short*)p; p += (size_t)N_WGM * 2;
    float* gi_tab = (float*)p; p += (size_t)N_GI * 4;
    float* idw    = (float*)p; p += (size_t)N_IDW * 4;
    float* WregT  = (float*)p; p += (size_t)N_WRT * 4;
    unsigned short* MsgB = (unsigned short*)p; p += (size_t)N_MSGB * 2;
    float* MsgF   = (float*)p; p += (size_t)N_MSGF * 4;
    unsigned short* HvB  = (unsigned short*)p; p += (size_t)BATCH * KP * 2;
    float* HvF    = (float*)p; p += (size_t)BATCH * KP * 4;
    unsigned int* adjcG  = (unsigned int*)p;  p += (size_t)N_ADJC * 4;
    unsigned short* Gbuf = (unsigned short*)p; p += (size_t)NN * BATCH * KP * 2;

    prep_kernel<<<4096, 256, 0, stream>>>(W_hh, Wg, Wm, W_ih, b_ih, b_hh, bg, W_reg, adj,
                                          Whh_p, Wgm_p, gi_tab, idw, WregT, MsgB, MsgF, adjcG);

    dim3 grd(BATCH / 16, KP / 64);   // 32 x 8 = 256 blocks
    for (int v = 0; v < NN; v++) {
        gru_kernel<<<grd, 512, 0, stream>>>(MsgB, MsgF, Whh_p, gi_tab, node_types, HvB, HvF, v);
        if (v < NN - 1)
            gate_kernel<<<grd, 512, 0, stream>>>(HvB, Wgm_p, idw, adjcG, Gbuf, MsgB, MsgF, v);
    }
    final_kernel<<<(BATCH * NN) / 256, 256, 0, stream>>>(HvF, WregT, b_reg, out);
}